// Round 3
// baseline (291.577 us; speedup 1.0000x reference)
//
#include <hip/hip_runtime.h>

typedef __attribute__((ext_vector_type(8))) short short8;
typedef __attribute__((ext_vector_type(4))) float float4_;

__device__ __forceinline__ unsigned short f2bf(float f) {
    unsigned u = __float_as_uint(f);
    u += 0x7FFFu + ((u >> 16) & 1u);   // round-to-nearest-even
    return (unsigned short)(u >> 16);
}

// ---------------------------------------------------------------------------
// Kernel 0: ROI-align 32x32 bilinear patch means -> garf[G][C].
// One block per (g,c); 4 samples/thread; wave shuffle + tiny LDS reduce.
// ---------------------------------------------------------------------------
__global__ void garf_kernel(const float* __restrict__ imgs,
                            const float* __restrict__ pros,
                            const int* __restrict__ imgbatch,
                            float* __restrict__ garf) {
    __shared__ float part[4];
    const int tid = threadIdx.x;
    int g = blockIdx.x >> 6, c = blockIdx.x & 63;
    int b = imgbatch[g];
    float cx = pros[g * 2 + 0], cy = pros[g * 2 + 1];
    int i = tid >> 3;                 // row 0..31
    int j0 = (tid & 7) * 4;           // 4 columns per thread
    float y = cy - 16.0f + (float)i + 0.5f;
    float yf = floorf(y);
    float wy1 = y - yf, wy0 = 1.0f - wy1;
    int iy0 = min(max((int)yf, 0), 191), iy1 = min(max((int)yf + 1, 0), 191);
    const float* base = imgs + (size_t)(b * 64 + c) * 36864;
    const float* r0 = base + iy0 * 192;
    const float* r1 = base + iy1 * 192;
    float sum = 0.0f;
#pragma unroll
    for (int jj = 0; jj < 4; ++jj) {
        float x = cx - 16.0f + (float)(j0 + jj) + 0.5f;
        float xf = floorf(x);
        float wx1 = x - xf, wx0 = 1.0f - wx1;
        int ix0 = min(max((int)xf, 0), 191), ix1 = min(max((int)xf + 1, 0), 191);
        sum += wy0 * (wx0 * r0[ix0] + wx1 * r0[ix1]) +
               wy1 * (wx0 * r1[ix0] + wx1 * r1[ix1]);
    }
    for (int s = 32; s >= 1; s >>= 1) sum += __shfl_xor(sum, s);
    if ((tid & 63) == 0) part[tid >> 6] = sum;
    __syncthreads();
    if (tid == 0)
        garf[g * 64 + c] = (part[0] + part[1] + part[2] + part[3]) * (1.0f / 1024.0f);
}

// ---------------------------------------------------------------------------
// Kernel 1: persistent fused MoE MLP, weights in REGISTERS.
// 256 blocks (1/CU), each owns a contiguous chunk of 64-vertex tiles.
// On type change each wave loads its 64-hid weight slice (fp32->bf16 inline):
//   w1f[24] + w2f[32] + w3f[8] short8 = 256 VGPRs. K-loops = LDS-B + MFMA only.
// Two 32KB LDS buffers ping-pong: feat -> bufP, h1 -> bufQ, h2 -> bufP.
// MFMA 16x16x32 bf16: A[m=lane&15][k=q*8+j], B[k=q*8+j][n=lane&15],
// D[m=q*4+r][n=lane&15].
// ---------------------------------------------------------------------------
struct MoEArgs {
    const float* x_verts;
    const int* gar;
    const int* idx[6];
    const float* W1;
    const float* W2;
    const float* W3;
    const float* garf;
    float* out;
    int cnt[6];
    int tile_end[6];
    int ntiles;
    int chunk;
};

__global__ __launch_bounds__(256, 1) void moe_kernel(MoEArgs a) {
    __shared__ __align__(16) char smem[65536 + 512];
    int* sidx = (int*)(smem + 65536);
    int* sg = sidx + 64;

    const int tid = threadIdx.x;
    const int lane = tid & 63, w = tid >> 6, q = lane >> 4, l = lane & 15;

    int start = blockIdx.x * a.chunk;
    int end = min(start + a.chunk, a.ntiles);

    short8 w1f[24], w2f[32], w3f[8];
    int tcur = -1;
    int p = 0;

    for (int tile = start; tile < end; ++tile, p ^= 1) {
        int t = 0;
        while (t < 5 && tile >= a.tile_end[t]) ++t;
        const int i0 = (tile - (t ? a.tile_end[t - 1] : 0)) * 64;
        const int cnt = a.cnt[t];
        const int* idx = a.idx[t];

        if (tid < 64) {
            int m = min(i0 + tid, cnt - 1);
            int vid = idx[m];
            sidx[tid] = vid;
            sg[tid] = a.gar[vid];
        }

        if (t != tcur) {   // wave-uniform: load this type's weight slice to regs
            tcur = t;
            const float* w1 = a.W1 + t * 49152;
            const float* w2 = a.W2 + t * 65536;
            const float* w3 = a.W3 + t * 768;
#pragma unroll
            for (int ks = 0; ks < 6; ++ks)
#pragma unroll
                for (int mt = 0; mt < 4; ++mt) {
                    const float* src = w1 + (ks * 32 + q * 8) * 256 + (w * 64 + mt * 16 + l);
                    short8 r;
#pragma unroll
                    for (int j = 0; j < 8; ++j) r[j] = (short)f2bf(src[j * 256]);
                    w1f[ks * 4 + mt] = r;
                }
#pragma unroll
            for (int ks = 0; ks < 8; ++ks)
#pragma unroll
                for (int mt = 0; mt < 4; ++mt) {
                    const float* src = w2 + (ks * 32 + q * 8) * 256 + (w * 64 + mt * 16 + l);
                    short8 r;
#pragma unroll
                    for (int j = 0; j < 8; ++j) r[j] = (short)f2bf(src[j * 256]);
                    w2f[ks * 4 + mt] = r;
                }
#pragma unroll
            for (int ks = 0; ks < 8; ++ks) {
                short8 r = {0, 0, 0, 0, 0, 0, 0, 0};
                if (l < 3) {   // exec-masked: lanes l>=3 issue no load (OOB-safe)
                    const float* src = w3 + (ks * 32 + q * 8) * 3 + l;
#pragma unroll
                    for (int j = 0; j < 8; ++j) r[j] = (short)f2bf(src[j * 3]);
                }
                w3f[ks] = r;
            }
        }
        __syncthreads();   // bar1: sidx/sg ready

        char* sF = smem + p * 32768;         // feat (stride 384), later h2 (stride 512)
        char* sH = smem + (p ^ 1) * 32768;   // h1 (stride 512)

        // ---- gather feat tile: 64 rows x 24 16B-units, swizzle u^(row&7) ----
        for (int e = tid; e < 1536; e += 256) {
            int m = e / 24, u = e - (e / 24) * 24;
            const float* src;
            if (u < 16) src = a.x_verts + (size_t)sidx[m] * 128 + u * 8;
            else        src = a.garf + sg[m] * 64 + (u - 16) * 8;
            float4 v0 = ((const float4*)src)[0];
            float4 v1 = ((const float4*)src)[1];
            short8 pk;
            pk[0] = f2bf(v0.x); pk[1] = f2bf(v0.y); pk[2] = f2bf(v0.z); pk[3] = f2bf(v0.w);
            pk[4] = f2bf(v1.x); pk[5] = f2bf(v1.y); pk[6] = f2bf(v1.z); pk[7] = f2bf(v1.w);
            *(short8*)(sF + m * 384 + ((u ^ (m & 7)) * 16)) = pk;
        }
        const int v3 = w * 16 + l;
        const int myvid = sidx[v3];          // cached for epilogue (pre-bar2)
        __syncthreads();   // bar2: feat ready

        // ---- layer 1: H1^T[256 hid][64 v], K=192, A from regs ----
        float4_ acc[4][4] = {};
#pragma unroll
        for (int ks = 0; ks < 6; ++ks) {
            short8 bfr[4];
#pragma unroll
            for (int nt = 0; nt < 4; ++nt) {
                int v = nt * 16 + l;
                bfr[nt] = *(const short8*)(sF + v * 384 + (((ks * 4 + q) ^ (v & 7)) * 16));
            }
#pragma unroll
            for (int mt = 0; mt < 4; ++mt)
#pragma unroll
                for (int nt = 0; nt < 4; ++nt)
                    acc[mt][nt] = __builtin_amdgcn_mfma_f32_16x16x32_bf16(
                        w1f[ks * 4 + mt], bfr[nt], acc[mt][nt], 0, 0, 0);
        }
        // relu -> h1 into sH (stride 512, unit swizzle ku^(v&7), 8B granule)
#pragma unroll
        for (int mt = 0; mt < 4; ++mt)
#pragma unroll
            for (int nt = 0; nt < 4; ++nt) {
                int v = nt * 16 + l;
                int hu8 = w * 16 + mt * 4 + q;   // hid/4
                int ku16 = hu8 >> 1, par = hu8 & 1;
                uint2 pk;
                pk.x = (unsigned)f2bf(fmaxf(acc[mt][nt][0], 0.0f)) |
                       ((unsigned)f2bf(fmaxf(acc[mt][nt][1], 0.0f)) << 16);
                pk.y = (unsigned)f2bf(fmaxf(acc[mt][nt][2], 0.0f)) |
                       ((unsigned)f2bf(fmaxf(acc[mt][nt][3], 0.0f)) << 16);
                *(uint2*)(sH + v * 512 + ((ku16 ^ (v & 7)) * 16) + par * 8) = pk;
            }
        __syncthreads();   // bar3: h1 ready (also: all feat reads done)

        // ---- layer 2: H2^T, K=256, A from regs; h2 -> sF (feat dead) ----
#pragma unroll
        for (int mt = 0; mt < 4; ++mt)
#pragma unroll
            for (int nt = 0; nt < 4; ++nt) acc[mt][nt] = float4_{0.f, 0.f, 0.f, 0.f};
#pragma unroll
        for (int ks = 0; ks < 8; ++ks) {
            short8 bfr[4];
#pragma unroll
            for (int nt = 0; nt < 4; ++nt) {
                int v = nt * 16 + l;
                bfr[nt] = *(const short8*)(sH + v * 512 + (((ks * 4 + q) ^ (v & 7)) * 16));
            }
#pragma unroll
            for (int mt = 0; mt < 4; ++mt)
#pragma unroll
                for (int nt = 0; nt < 4; ++nt)
                    acc[mt][nt] = __builtin_amdgcn_mfma_f32_16x16x32_bf16(
                        w2f[ks * 4 + mt], bfr[nt], acc[mt][nt], 0, 0, 0);
        }
#pragma unroll
        for (int mt = 0; mt < 4; ++mt)
#pragma unroll
            for (int nt = 0; nt < 4; ++nt) {
                int v = nt * 16 + l;
                int hu8 = w * 16 + mt * 4 + q;
                int ku16 = hu8 >> 1, par = hu8 & 1;
                uint2 pk;
                pk.x = (unsigned)f2bf(fmaxf(acc[mt][nt][0], 0.0f)) |
                       ((unsigned)f2bf(fmaxf(acc[mt][nt][1], 0.0f)) << 16);
                pk.y = (unsigned)f2bf(fmaxf(acc[mt][nt][2], 0.0f)) |
                       ((unsigned)f2bf(fmaxf(acc[mt][nt][3], 0.0f)) << 16);
                *(uint2*)(sF + v * 512 + ((ku16 ^ (v & 7)) * 16) + par * 8) = pk;
            }
        __syncthreads();   // bar4: h2 ready (also: all h1 reads done)

        // ---- layer 3: wave w owns vertices v3=w*16+l, full K=256 ----
        float4_ acc3 = {};
#pragma unroll
        for (int ks = 0; ks < 8; ++ks) {
            short8 b3 = *(const short8*)(sF + v3 * 512 + (((ks * 4 + q) ^ (v3 & 7)) * 16));
            acc3 = __builtin_amdgcn_mfma_f32_16x16x32_bf16(w3f[ks], b3, acc3, 0, 0, 0);
        }
        // D[m=q*4+r][n=l]: q==0 lanes hold outdims 0..3 for vertex v3
        if (q == 0 && i0 + v3 < cnt) {
            float* o = a.out + (size_t)myvid * 3;
            o[0] = acc3[0]; o[1] = acc3[1]; o[2] = acc3[2];
        }
        // no end barrier needed: next sidx write is WAR-separated by bar2..bar4;
        // next gather writes sH-region (all h1 reads done at bar4); next h1
        // writes current sF-region only after next bar2 (all L3 reads done).
    }
}

// ---------------------------------------------------------------------------
extern "C" void kernel_launch(void* const* d_in, const int* in_sizes, int n_in,
                              void* d_out, int out_size, void* d_ws, size_t ws_size,
                              hipStream_t stream) {
    const float* imgs    = (const float*)d_in[0];
    const float* pros    = (const float*)d_in[1];
    const float* x_verts = (const float*)d_in[2];
    const float* W1      = (const float*)d_in[3];
    const float* W2      = (const float*)d_in[4];
    const float* W3      = (const float*)d_in[5];
    const int* imgbatch  = (const int*)d_in[6];
    const int* gar       = (const int*)d_in[7];

    float* garf = (float*)d_ws;   // 24*64*4 = 6144 B

    garf_kernel<<<24 * 64, 256, 0, stream>>>(imgs, pros, imgbatch, garf);

    MoEArgs a;
    a.x_verts = x_verts;
    a.gar = gar;
    for (int t = 0; t < 6; ++t) a.idx[t] = (const int*)d_in[8 + t];
    a.W1 = W1; a.W2 = W2; a.W3 = W3;
    a.garf = garf;
    a.out = (float*)d_out;
    int tiles = 0;
    for (int t = 0; t < 6; ++t) {
        a.cnt[t] = in_sizes[8 + t];
        tiles += (a.cnt[t] + 63) / 64;
        a.tile_end[t] = tiles;
    }
    a.ntiles = tiles;
    a.chunk = (tiles + 255) / 256;
    moe_kernel<<<256, 256, 0, stream>>>(a);
}

// Round 4
// 288.538 us; speedup vs baseline: 1.0105x; 1.0105x over previous
//
#include <hip/hip_runtime.h>

typedef __attribute__((ext_vector_type(8))) short short8;
typedef __attribute__((ext_vector_type(4))) float float4_;

__device__ __forceinline__ unsigned short f2bf(float f) {
    unsigned u = __float_as_uint(f);
    u += 0x7FFFu + ((u >> 16) & 1u);   // round-to-nearest-even
    return (unsigned short)(u >> 16);
}

// ---------------------------------------------------------------------------
// Kernel 0: ROI-align 32x32 bilinear patch means -> garf[G][C].
// One block per (g,c); 4 samples/thread; wave shuffle + tiny LDS reduce.
// ---------------------------------------------------------------------------
__global__ void garf_kernel(const float* __restrict__ imgs,
                            const float* __restrict__ pros,
                            const int* __restrict__ imgbatch,
                            float* __restrict__ garf) {
    __shared__ float part[4];
    const int tid = threadIdx.x;
    int g = blockIdx.x >> 6, c = blockIdx.x & 63;
    int b = imgbatch[g];
    float cx = pros[g * 2 + 0], cy = pros[g * 2 + 1];
    int i = tid >> 3;                 // row 0..31
    int j0 = (tid & 7) * 4;           // 4 columns per thread
    float y = cy - 16.0f + (float)i + 0.5f;
    float yf = floorf(y);
    float wy1 = y - yf, wy0 = 1.0f - wy1;
    int iy0 = min(max((int)yf, 0), 191), iy1 = min(max((int)yf + 1, 0), 191);
    const float* base = imgs + (size_t)(b * 64 + c) * 36864;
    const float* r0 = base + iy0 * 192;
    const float* r1 = base + iy1 * 192;
    float sum = 0.0f;
#pragma unroll
    for (int jj = 0; jj < 4; ++jj) {
        float x = cx - 16.0f + (float)(j0 + jj) + 0.5f;
        float xf = floorf(x);
        float wx1 = x - xf, wx0 = 1.0f - wx1;
        int ix0 = min(max((int)xf, 0), 191), ix1 = min(max((int)xf + 1, 0), 191);
        sum += wy0 * (wx0 * r0[ix0] + wx1 * r0[ix1]) +
               wy1 * (wx0 * r1[ix0] + wx1 * r1[ix1]);
    }
    for (int s = 32; s >= 1; s >>= 1) sum += __shfl_xor(sum, s);
    if ((tid & 63) == 0) part[tid >> 6] = sum;
    __syncthreads();
    if (tid == 0)
        garf[g * 64 + c] = (part[0] + part[1] + part[2] + part[3]) * (1.0f / 1024.0f);
}

// ---------------------------------------------------------------------------
// Kernel 1: persistent fused MoE MLP; 512-thread blocks (8 waves, 2/SIMD).
// Each wave owns a 32-hid slice of W1/W2 in regs (12+16 short8) + K-quarter
// of padded W3 (4 short8) = 128 weight VGPRs -> total ~230, 2 waves/SIMD.
// All tile indices (vid, gar) preloaded to LDS once per block (one 2-chain).
// Per tile: gather feat(bf16,swizzled) -> barA -> L1 -> h1 -> barB -> L2 ->
// h2 -> barC -> L3 (K split over wave-quartets) -> barD -> LDS reduce -> out.
// MFMA 16x16x32 bf16: A[m=lane&15][k=q*8+j], B[k=q*8+j][n=lane&15],
// D[m=q*4+r][n=lane&15].
// ---------------------------------------------------------------------------
#define NBLK 256
struct MoEArgs {
    const float* x_verts;
    const int* gar;
    const int* idx[6];
    const float* W1;
    const float* W2;
    const float* W3;
    const float* garf;
    float* out;
    int cnt[6];
    int tile_end[6];
    int ntiles;
};

__global__ __launch_bounds__(512, 2) void moe_kernel(MoEArgs a) {
    __shared__ __align__(16) char smem[65536];          // 2 x 32KB ping-pong
    __shared__ int sidx_all[448], sg_all[448];          // up to 7 tiles x 64
    __shared__ float pb[2 * 64 * 4];                    // L3 partials

    const int tid = threadIdx.x;
    const int lane = tid & 63, w = tid >> 6, q = lane >> 4, l = lane & 15;

    const int start = (blockIdx.x * a.ntiles) / NBLK;
    const int end = ((int)(blockIdx.x + 1) * a.ntiles) / NBLK;
    const int nt_blk = end - start;

    // ---- preload ALL tile indices for this block (single 2-chain) ----
    if (tid < nt_blk * 64) {
        int s = tid >> 6, lm = tid & 63;
        int tile = start + s;
        int t = 0;
        while (t < 5 && tile >= a.tile_end[t]) ++t;
        int i0 = (tile - (t ? a.tile_end[t - 1] : 0)) * 64;
        int m = min(i0 + lm, a.cnt[t] - 1);
        int vid = a.idx[t][m];
        sidx_all[tid] = vid;
        sg_all[tid] = a.gar[vid];
    }

    short8 w1f[12], w2f[16], w3f[4];
    const int kh = w >> 2;            // L3 K-half of this wave
    const int vs = w & 3;             // L3 vertex 16-slice
    int tcur = -1;
    int p = 0;
    __syncthreads();

    for (int s = 0; s < nt_blk; ++s, p ^= 1) {
        const int tile = start + s;
        int t = 0;
        while (t < 5 && tile >= a.tile_end[t]) ++t;
        const int i0 = (tile - (t ? a.tile_end[t - 1] : 0)) * 64;
        const int cnt = a.cnt[t];
        const int* sidx = sidx_all + s * 64;
        const int* sg = sg_all + s * 64;

        if (t != tcur) {   // wave-uniform: load this type's weight slice
            tcur = t;
            const float* w1 = a.W1 + t * 49152;
            const float* w2 = a.W2 + t * 65536;
            const float* w3 = a.W3 + t * 768;
#pragma unroll
            for (int ks = 0; ks < 6; ++ks)
#pragma unroll
                for (int mt = 0; mt < 2; ++mt) {
                    const float* src = w1 + (ks * 32 + q * 8) * 256 + (w * 32 + mt * 16 + l);
                    short8 r;
#pragma unroll
                    for (int j = 0; j < 8; ++j) r[j] = (short)f2bf(src[j * 256]);
                    w1f[ks * 2 + mt] = r;
                }
#pragma unroll
            for (int ks = 0; ks < 8; ++ks)
#pragma unroll
                for (int mt = 0; mt < 2; ++mt) {
                    const float* src = w2 + (ks * 32 + q * 8) * 256 + (w * 32 + mt * 16 + l);
                    short8 r;
#pragma unroll
                    for (int j = 0; j < 8; ++j) r[j] = (short)f2bf(src[j * 256]);
                    w2f[ks * 2 + mt] = r;
                }
#pragma unroll
            for (int i = 0; i < 4; ++i) {
                int ks = kh * 4 + i;
                short8 r = {0, 0, 0, 0, 0, 0, 0, 0};
                if (l < 3) {
                    const float* src = w3 + (ks * 32 + q * 8) * 3 + l;
#pragma unroll
                    for (int j = 0; j < 8; ++j) r[j] = (short)f2bf(src[j * 3]);
                }
                w3f[i] = r;
            }
        }

        char* sF = smem + p * 32768;         // feat (stride 384); later h2 (stride 512)
        char* sH = smem + (p ^ 1) * 32768;   // h1 (stride 512)

        // ---- gather feat: 1536 16B-units, 3/thread, batched loads ----
        {
            float4 va[3][2];
            int mm[3], uu[3];
#pragma unroll
            for (int i = 0; i < 3; ++i) {
                int e = tid + i * 512;
                int m = e / 24, u = e - m * 24;
                mm[i] = m; uu[i] = u;
                const float* src;
                if (u < 16) src = a.x_verts + (size_t)sidx[m] * 128 + u * 8;
                else        src = a.garf + sg[m] * 64 + (u - 16) * 8;
                va[i][0] = ((const float4*)src)[0];
                va[i][1] = ((const float4*)src)[1];
            }
#pragma unroll
            for (int i = 0; i < 3; ++i) {
                short8 pk;
                pk[0] = f2bf(va[i][0].x); pk[1] = f2bf(va[i][0].y);
                pk[2] = f2bf(va[i][0].z); pk[3] = f2bf(va[i][0].w);
                pk[4] = f2bf(va[i][1].x); pk[5] = f2bf(va[i][1].y);
                pk[6] = f2bf(va[i][1].z); pk[7] = f2bf(va[i][1].w);
                *(short8*)(sF + mm[i] * 384 + ((uu[i] ^ (mm[i] & 7)) * 16)) = pk;
            }
        }
        __syncthreads();   // barA: feat ready

        // ---- layer 1: hid slice w*32.., K=192 ----
        float4_ acc[2][4] = {};
#pragma unroll
        for (int ks = 0; ks < 6; ++ks) {
            short8 bfr[4];
#pragma unroll
            for (int nt = 0; nt < 4; ++nt) {
                int v = nt * 16 + l;
                bfr[nt] = *(const short8*)(sF + v * 384 + (((ks * 4 + q) ^ (v & 7)) * 16));
            }
#pragma unroll
            for (int mt = 0; mt < 2; ++mt)
#pragma unroll
                for (int nt = 0; nt < 4; ++nt)
                    acc[mt][nt] = __builtin_amdgcn_mfma_f32_16x16x32_bf16(
                        w1f[ks * 2 + mt], bfr[nt], acc[mt][nt], 0, 0, 0);
        }
        // relu -> h1 into sH (stride 512, unit swizzle ku^(v&7), 8B granule)
#pragma unroll
        for (int mt = 0; mt < 2; ++mt)
#pragma unroll
            for (int nt = 0; nt < 4; ++nt) {
                int v = nt * 16 + l;
                int hu8 = w * 8 + mt * 4 + q;   // hid/4
                int ku16 = hu8 >> 1, par = hu8 & 1;
                uint2 pk;
                pk.x = (unsigned)f2bf(fmaxf(acc[mt][nt][0], 0.0f)) |
                       ((unsigned)f2bf(fmaxf(acc[mt][nt][1], 0.0f)) << 16);
                pk.y = (unsigned)f2bf(fmaxf(acc[mt][nt][2], 0.0f)) |
                       ((unsigned)f2bf(fmaxf(acc[mt][nt][3], 0.0f)) << 16);
                *(uint2*)(sH + v * 512 + ((ku16 ^ (v & 7)) * 16) + par * 8) = pk;
            }
        __syncthreads();   // barB: h1 ready (feat reads done)

        // ---- layer 2: K=256; h2 -> sF (feat dead) ----
#pragma unroll
        for (int mt = 0; mt < 2; ++mt)
#pragma unroll
            for (int nt = 0; nt < 4; ++nt) acc[mt][nt] = float4_{0.f, 0.f, 0.f, 0.f};
#pragma unroll
        for (int ks = 0; ks < 8; ++ks) {
            short8 bfr[4];
#pragma unroll
            for (int nt = 0; nt < 4; ++nt) {
                int v = nt * 16 + l;
                bfr[nt] = *(const short8*)(sH + v * 512 + (((ks * 4 + q) ^ (v & 7)) * 16));
            }
#pragma unroll
            for (int mt = 0; mt < 2; ++mt)
#pragma unroll
                for (int nt = 0; nt < 4; ++nt)
                    acc[mt][nt] = __builtin_amdgcn_mfma_f32_16x16x32_bf16(
                        w2f[ks * 2 + mt], bfr[nt], acc[mt][nt], 0, 0, 0);
        }
#pragma unroll
        for (int mt = 0; mt < 2; ++mt)
#pragma unroll
            for (int nt = 0; nt < 4; ++nt) {
                int v = nt * 16 + l;
                int hu8 = w * 8 + mt * 4 + q;
                int ku16 = hu8 >> 1, par = hu8 & 1;
                uint2 pk;
                pk.x = (unsigned)f2bf(fmaxf(acc[mt][nt][0], 0.0f)) |
                       ((unsigned)f2bf(fmaxf(acc[mt][nt][1], 0.0f)) << 16);
                pk.y = (unsigned)f2bf(fmaxf(acc[mt][nt][2], 0.0f)) |
                       ((unsigned)f2bf(fmaxf(acc[mt][nt][3], 0.0f)) << 16);
                *(uint2*)(sF + v * 512 + ((ku16 ^ (v & 7)) * 16) + par * 8) = pk;
            }
        __syncthreads();   // barC: h2 ready (h1 reads done)

        // ---- layer 3: wave = (K-half kh) x (vertex slice vs), 4 MFMAs ----
        float4_ acc3 = {};
        const int v3 = vs * 16 + l;
#pragma unroll
        for (int i = 0; i < 4; ++i) {
            int ks = kh * 4 + i;
            short8 b3 = *(const short8*)(sF + v3 * 512 + (((ks * 4 + q) ^ (v3 & 7)) * 16));
            acc3 = __builtin_amdgcn_mfma_f32_16x16x32_bf16(w3f[i], b3, acc3, 0, 0, 0);
        }
        if (q == 0) {   // D[m=r][n=l]: rows 0..2 are the out dims
            float* d = pb + kh * 256 + v3 * 4;
            d[0] = acc3[0]; d[1] = acc3[1]; d[2] = acc3[2];
        }
        __syncthreads();   // barD: partials ready

        if (tid < 192) {
            int v = tid / 3, j = tid - v * 3;
            if (i0 + v < cnt) {
                float sum = pb[v * 4 + j] + pb[256 + v * 4 + j];
                a.out[(size_t)sidx[v] * 3 + j] = sum;
            }
        }
        // next gather writes sH region (h1 dead since barC); pb/sidx reads
        // complete before next barA; h2 region overwritten only after barA.
    }
}

// ---------------------------------------------------------------------------
extern "C" void kernel_launch(void* const* d_in, const int* in_sizes, int n_in,
                              void* d_out, int out_size, void* d_ws, size_t ws_size,
                              hipStream_t stream) {
    const float* imgs    = (const float*)d_in[0];
    const float* pros    = (const float*)d_in[1];
    const float* x_verts = (const float*)d_in[2];
    const float* W1      = (const float*)d_in[3];
    const float* W2      = (const float*)d_in[4];
    const float* W3      = (const float*)d_in[5];
    const int* imgbatch  = (const int*)d_in[6];
    const int* gar       = (const int*)d_in[7];

    float* garf = (float*)d_ws;   // 24*64*4 = 6144 B

    garf_kernel<<<24 * 64, 256, 0, stream>>>(imgs, pros, imgbatch, garf);

    MoEArgs a;
    a.x_verts = x_verts;
    a.gar = gar;
    for (int t = 0; t < 6; ++t) a.idx[t] = (const int*)d_in[8 + t];
    a.W1 = W1; a.W2 = W2; a.W3 = W3;
    a.garf = garf;
    a.out = (float*)d_out;
    int tiles = 0;
    for (int t = 0; t < 6; ++t) {
        a.cnt[t] = in_sizes[8 + t];
        tiles += (a.cnt[t] + 63) / 64;
        a.tile_end[t] = tiles;
    }
    a.ntiles = tiles;
    moe_kernel<<<NBLK, 512, 0, stream>>>(a);
}

// Round 5
// 271.923 us; speedup vs baseline: 1.0723x; 1.0611x over previous
//
#include <hip/hip_runtime.h>

typedef __attribute__((ext_vector_type(8))) short short8;
typedef __attribute__((ext_vector_type(4))) float float4_;

__device__ __forceinline__ unsigned short f2bf(float f) {
    unsigned u = __float_as_uint(f);
    u += 0x7FFFu + ((u >> 16) & 1u);   // round-to-nearest-even
    return (unsigned short)(u >> 16);
}

#define GARF_BLOCKS 1536   // G(24) * C(64)
#define PREP_BLOCKS 2784   // ceil(712704 / 256)

// ---------------------------------------------------------------------------
// Fused kernel 0: (a) ROI-align 32x32 bilinear patch means -> garf[G][C]
//                 (b) weights fp32 -> bf16, transposed to [N][K]
// ---------------------------------------------------------------------------
__global__ void prep_garf(const float* __restrict__ imgs,
                          const float* __restrict__ pros,
                          const int* __restrict__ imgbatch,
                          const float* __restrict__ W1,
                          const float* __restrict__ W2,
                          const float* __restrict__ W3,
                          unsigned short* __restrict__ w1t,
                          unsigned short* __restrict__ w2t,
                          unsigned short* __restrict__ w3t,
                          float* __restrict__ garf) {
    const int tid = threadIdx.x;
    if (blockIdx.x < GARF_BLOCKS) {
        __shared__ float part[4];
        int pc = blockIdx.x;
        int g = pc >> 6, c = pc & 63;
        int b = imgbatch[g];
        float cx = pros[g * 2 + 0], cy = pros[g * 2 + 1];
        int i = tid >> 3;                 // row 0..31
        int j0 = (tid & 7) * 4;           // 4 columns per thread
        float y = cy - 16.0f + (float)i + 0.5f;
        float yf = floorf(y);
        float wy1 = y - yf, wy0 = 1.0f - wy1;
        int iy0 = min(max((int)yf, 0), 191), iy1 = min(max((int)yf + 1, 0), 191);
        const float* base = imgs + (size_t)(b * 64 + c) * 36864;
        const float* r0 = base + iy0 * 192;
        const float* r1 = base + iy1 * 192;
        float sum = 0.0f;
#pragma unroll
        for (int jj = 0; jj < 4; ++jj) {
            float x = cx - 16.0f + (float)(j0 + jj) + 0.5f;
            float xf = floorf(x);
            float wx1 = x - xf, wx0 = 1.0f - wx1;
            int ix0 = min(max((int)xf, 0), 191), ix1 = min(max((int)xf + 1, 0), 191);
            sum += wy0 * (wx0 * r0[ix0] + wx1 * r0[ix1]) +
                   wy1 * (wx0 * r1[ix0] + wx1 * r1[ix1]);
        }
        for (int s = 32; s >= 1; s >>= 1) sum += __shfl_xor(sum, s);
        if ((tid & 63) == 0) part[tid >> 6] = sum;
        __syncthreads();
        if (tid == 0)
            garf[g * 64 + c] = (part[0] + part[1] + part[2] + part[3]) * (1.0f / 1024.0f);
    } else {
        int id = (blockIdx.x - GARF_BLOCKS) * 256 + tid;
        if (id < 294912) {                       // W1: 6*192*256, src [t][k][n]
            int t = id / 49152, r = id % 49152;
            int k = r >> 8, n = r & 255;
            w1t[t * 49152 + n * 192 + k] = f2bf(W1[id]);
        } else if (id < 688128) {                // W2: 6*256*256
            int i2 = id - 294912;
            int t = i2 >> 16, r = i2 & 65535;
            int k = r >> 8, n = r & 255;
            w2t[t * 65536 + n * 256 + k] = f2bf(W2[i2]);
        } else if (id < 712704) {                // w3t dest: 6*16*256 (n>=3 zero)
            int i3 = id - 688128;
            int t = i3 >> 12, r = i3 & 4095;
            int n = r >> 8, k = r & 255;
            w3t[i3] = (n < 3) ? f2bf(W3[t * 768 + k * 3 + n]) : (unsigned short)0;
        }
    }
}

// ---------------------------------------------------------------------------
// Kernel 1: fused MoE MLP, transposed compute (weights=A from L2, vertices=B
// from LDS), ONE tile per block, explicit ILP:
//  - gather: 1 idx/gar load per thread, 12 batched float4 loads
//  - K-loops: register double-buffer of A(L2) and B(LDS) fragments
//  - L3: all frags batch-loaded, out stored from regs
// Single 32KB LDS buffer in-place (feat -> h1 -> h2) with 5 barriers.
// MFMA 16x16x32 bf16: A[m=lane&15][k=q*8+j], B[k=q*8+j][n=lane&15],
// D[m=q*4+r][n=lane&15].
// ---------------------------------------------------------------------------
struct MoEArgs {
    const float* x_verts;
    const int* gar;
    const int* idx[6];
    const unsigned short* w1t;
    const unsigned short* w2t;
    const unsigned short* w3t;
    const float* garf;
    float* out;
    int cnt[6];
    int tile_end[6];
};

__global__ __launch_bounds__(256, 3) void moe_kernel(MoEArgs a) {
    __shared__ __align__(16) char sF[32768];   // feat(64x384) -> h1/h2(64x512)

    const int tid = threadIdx.x;
    const int lane = tid & 63, w = tid >> 6, q = lane >> 4, l = lane & 15;

    int bt = blockIdx.x;
    int t = 0;
    while (t < 5 && bt >= a.tile_end[t]) ++t;
    const int i0 = (bt - (t ? a.tile_end[t - 1] : 0)) * 64;
    const int cnt = a.cnt[t];
    const int* idx = a.idx[t];

    // vid for the epilogue store (independent load, issued early)
    const int v3 = w * 16 + l;
    const int vid3 = idx[min(i0 + v3, cnt - 1)];

    // ---- gather: thread owns quarter-row m=tid>>2, units (tid&3)*6..+5 ----
    {
        int m = tid >> 2;
        int vid = idx[min(i0 + m, cnt - 1)];
        int g = a.gar[vid];
        const float* vsrc = a.x_verts + (size_t)vid * 128;
        const float* gsrc = a.garf + g * 64;
        int u0 = (tid & 3) * 6;
        float4 v[6][2];
#pragma unroll
        for (int i = 0; i < 6; ++i) {
            int u = u0 + i;
            const float* s = (u < 16) ? (vsrc + u * 8) : (gsrc + (u - 16) * 8);
            v[i][0] = ((const float4*)s)[0];
            v[i][1] = ((const float4*)s)[1];
        }
#pragma unroll
        for (int i = 0; i < 6; ++i) {
            int u = u0 + i;
            short8 pk;
            pk[0] = f2bf(v[i][0].x); pk[1] = f2bf(v[i][0].y);
            pk[2] = f2bf(v[i][0].z); pk[3] = f2bf(v[i][0].w);
            pk[4] = f2bf(v[i][1].x); pk[5] = f2bf(v[i][1].y);
            pk[6] = f2bf(v[i][1].z); pk[7] = f2bf(v[i][1].w);
            *(short8*)(sF + m * 384 + ((u ^ (m & 7)) * 16)) = pk;
        }
    }
    __syncthreads();   // bar1: feat ready

    // ---- layer 1: hid slice w*64.., K=192, reg-double-buffered ----
    float4_ acc[4][4] = {};
    {
        const unsigned short* w1 = a.w1t + (size_t)t * 49152;
        const unsigned short* pA[4];
#pragma unroll
        for (int nt = 0; nt < 4; ++nt)
            pA[nt] = w1 + (w * 64 + nt * 16 + l) * 192 + q * 8;
        short8 A0[4], A1[4], B0[4], B1[4];
#pragma unroll
        for (int nt = 0; nt < 4; ++nt) {
            A0[nt] = *(const short8*)(pA[nt]);
            int v = nt * 16 + l;
            B0[nt] = *(const short8*)(sF + v * 384 + ((q ^ (v & 7)) * 16));
        }
#pragma unroll
        for (int ks = 0; ks < 6; ++ks) {
            if (ks < 5) {
#pragma unroll
                for (int nt = 0; nt < 4; ++nt) {
                    A1[nt] = *(const short8*)(pA[nt] + (ks + 1) * 32);
                    int v = nt * 16 + l;
                    B1[nt] = *(const short8*)(sF + v * 384 +
                              ((((ks + 1) * 4 + q) ^ (v & 7)) * 16));
                }
            }
#pragma unroll
            for (int mt = 0; mt < 4; ++mt)
#pragma unroll
                for (int nt = 0; nt < 4; ++nt)
                    acc[mt][nt] = __builtin_amdgcn_mfma_f32_16x16x32_bf16(
                        A0[mt], B0[nt], acc[mt][nt], 0, 0, 0);
#pragma unroll
            for (int nt = 0; nt < 4; ++nt) { A0[nt] = A1[nt]; B0[nt] = B1[nt]; }
        }
    }
    __syncthreads();   // bar2: all feat reads done

    // relu -> h1 in-place (stride 512, 16B-unit swizzle ku^(v&7), 8B granule)
#pragma unroll
    for (int mt = 0; mt < 4; ++mt)
#pragma unroll
        for (int nt = 0; nt < 4; ++nt) {
            int v = nt * 16 + l;
            int hu8 = w * 16 + mt * 4 + q;   // hid/4
            int ku16 = hu8 >> 1, par = hu8 & 1;
            uint2 pk;
            pk.x = (unsigned)f2bf(fmaxf(acc[mt][nt][0], 0.0f)) |
                   ((unsigned)f2bf(fmaxf(acc[mt][nt][1], 0.0f)) << 16);
            pk.y = (unsigned)f2bf(fmaxf(acc[mt][nt][2], 0.0f)) |
                   ((unsigned)f2bf(fmaxf(acc[mt][nt][3], 0.0f)) << 16);
            *(uint2*)(sF + v * 512 + ((ku16 ^ (v & 7)) * 16) + par * 8) = pk;
        }
    __syncthreads();   // bar3: h1 ready

    // ---- layer 2: K=256, reg-double-buffered ----
    float4_ acc2[4][4] = {};
    {
        const unsigned short* w2 = a.w2t + (size_t)t * 65536;
        const unsigned short* pA[4];
#pragma unroll
        for (int nt = 0; nt < 4; ++nt)
            pA[nt] = w2 + (w * 64 + nt * 16 + l) * 256 + q * 8;
        short8 A0[4], A1[4], B0[4], B1[4];
#pragma unroll
        for (int nt = 0; nt < 4; ++nt) {
            A0[nt] = *(const short8*)(pA[nt]);
            int v = nt * 16 + l;
            B0[nt] = *(const short8*)(sF + v * 512 + ((q ^ (v & 7)) * 16));
        }
#pragma unroll
        for (int ks = 0; ks < 8; ++ks) {
            if (ks < 7) {
#pragma unroll
                for (int nt = 0; nt < 4; ++nt) {
                    A1[nt] = *(const short8*)(pA[nt] + (ks + 1) * 32);
                    int v = nt * 16 + l;
                    B1[nt] = *(const short8*)(sF + v * 512 +
                              ((((ks + 1) * 4 + q) ^ (v & 7)) * 16));
                }
            }
#pragma unroll
            for (int mt = 0; mt < 4; ++mt)
#pragma unroll
                for (int nt = 0; nt < 4; ++nt)
                    acc2[mt][nt] = __builtin_amdgcn_mfma_f32_16x16x32_bf16(
                        A0[mt], B0[nt], acc2[mt][nt], 0, 0, 0);
#pragma unroll
            for (int nt = 0; nt < 4; ++nt) { A0[nt] = A1[nt]; B0[nt] = B1[nt]; }
        }
    }
    __syncthreads();   // bar4: all h1 reads done

#pragma unroll
    for (int mt = 0; mt < 4; ++mt)
#pragma unroll
        for (int nt = 0; nt < 4; ++nt) {
            int v = nt * 16 + l;
            int hu8 = w * 16 + mt * 4 + q;
            int ku16 = hu8 >> 1, par = hu8 & 1;
            uint2 pk;
            pk.x = (unsigned)f2bf(fmaxf(acc2[mt][nt][0], 0.0f)) |
                   ((unsigned)f2bf(fmaxf(acc2[mt][nt][1], 0.0f)) << 16);
            pk.y = (unsigned)f2bf(fmaxf(acc2[mt][nt][2], 0.0f)) |
                   ((unsigned)f2bf(fmaxf(acc2[mt][nt][3], 0.0f)) << 16);
            *(uint2*)(sF + v * 512 + ((ku16 ^ (v & 7)) * 16) + par * 8) = pk;
        }
    __syncthreads();   // bar5: h2 ready

    // ---- layer 3: wave w owns vertices v3=w*16+l, full K, all-batched ----
    {
        const unsigned short* w3 = a.w3t + (size_t)t * 4096;
        short8 A3[8], B3[8];
#pragma unroll
        for (int ks = 0; ks < 8; ++ks) {
            A3[ks] = *(const short8*)(w3 + l * 256 + ks * 32 + q * 8);
            B3[ks] = *(const short8*)(sF + v3 * 512 + (((ks * 4 + q) ^ (v3 & 7)) * 16));
        }
        float4_ acc3 = {};
#pragma unroll
        for (int ks = 0; ks < 8; ++ks)
            acc3 = __builtin_amdgcn_mfma_f32_16x16x32_bf16(A3[ks], B3[ks], acc3, 0, 0, 0);
        // D[m=q*4+r][n=l]: q==0 lanes hold outdims 0..3 for vertex v3
        if (q == 0 && i0 + v3 < cnt) {
            float* o = a.out + (size_t)vid3 * 3;
            o[0] = acc3[0]; o[1] = acc3[1]; o[2] = acc3[2];
        }
    }
}

// ---------------------------------------------------------------------------
extern "C" void kernel_launch(void* const* d_in, const int* in_sizes, int n_in,
                              void* d_out, int out_size, void* d_ws, size_t ws_size,
                              hipStream_t stream) {
    const float* imgs    = (const float*)d_in[0];
    const float* pros    = (const float*)d_in[1];
    const float* x_verts = (const float*)d_in[2];
    const float* W1      = (const float*)d_in[3];
    const float* W2      = (const float*)d_in[4];
    const float* W3      = (const float*)d_in[5];
    const int* imgbatch  = (const int*)d_in[6];
    const int* gar       = (const int*)d_in[7];

    // ws layout (16B-aligned): w1t | w2t | w3t | garf
    unsigned short* w1t = (unsigned short*)d_ws;                       // 589824 B
    unsigned short* w2t = (unsigned short*)((char*)d_ws + 589824);     // 786432 B
    unsigned short* w3t = (unsigned short*)((char*)d_ws + 1376256);    // 49152 B
    float* garf         = (float*)((char*)d_ws + 1425408);             // 6144 B

    prep_garf<<<GARF_BLOCKS + PREP_BLOCKS, 256, 0, stream>>>(
        imgs, pros, imgbatch, W1, W2, W3, w1t, w2t, w3t, garf);

    MoEArgs a;
    a.x_verts = x_verts;
    a.gar = gar;
    for (int t = 0; t < 6; ++t) a.idx[t] = (const int*)d_in[8 + t];
    a.w1t = w1t; a.w2t = w2t; a.w3t = w3t;
    a.garf = garf;
    a.out = (float*)d_out;
    int tiles = 0;
    for (int t = 0; t < 6; ++t) {
        a.cnt[t] = in_sizes[8 + t];
        tiles += (a.cnt[t] + 63) / 64;
        a.tile_end[t] = tiles;
    }
    moe_kernel<<<tiles, 256, 0, stream>>>(a);
}